// Round 7
// baseline (73.980 us; speedup 1.0000x reference)
//
#include <hip/hip_runtime.h>
#include <hip/hip_bf16.h>
#include <float.h>
#include <limits.h>

#define FEAT       256
#define GAMMA_F    0.1f
#define EPS_F      1e-8f
#define KSEL       64        // BUDGET
#define NBUCK      4096      // 12-bit histogram of flipped-float keys
#define KSHIFT     20        // key >> KSHIFT -> bucket
#define NREP       16        // histogram replicas (same-address chains ~5)
#define NB1        1024      // persistent score blocks (4096 waves)
#define NB3        64        // select blocks
#define CPW        4         // candidates per wave
#define BCAP       64        // per-block survivor region (expected ~2 used)
#define CAP        4096      // final assembly capacity (= NB3 * BCAP)

// Monotonic float -> uint transform (ascending order preserved).
__device__ __forceinline__ unsigned key_of(float v) {
    unsigned u = __float_as_uint(v);
    return u ^ ((u >> 31) ? 0xFFFFFFFFu : 0x80000000u);
}

__device__ __forceinline__ bool comes_first(float va, int ia, float vb, int ib) {
    return (va > vb) || (va == vb && ia < ib);
}

// ---------------------------------------------------------------------------
// Kernel 1: fused edge scores + replicated histogram. Persistent grid (1024
// blocks = 4096 waves): each wave grid-strides over groups of CPW=4
// candidates (4 independent 1 KB row-gathers in flight). ||inj|| reduced once
// per wave. Lane 0 stores 4 scores as one float4 AND issues 4 fire-and-forget
// hist atomics into replica (wid & 15) -- round-3's fused-hist failure was
// NREP=1 (~250-deep same-address chains); at NREP=16 the per-burst chain
// depth is ~5, which is noise. Histogram zeros come from a prior memset node
// (kernel boundary ordering), since K1 both writes and depends on them.
// ---------------------------------------------------------------------------
__global__ __launch_bounds__(256) void edge_score_kernel(
    const float* __restrict__ infl,
    const float* __restrict__ feats,
    const int*   __restrict__ cand,
    const float* __restrict__ inj,
    float*       __restrict__ scores,   // d_out + KSEL
    unsigned*    __restrict__ ghist,    // [NBUCK][NREP], pre-zeroed
    int num_cand)
{
    const int gtid = blockIdx.x * blockDim.x + threadIdx.x;
    const int lane    = threadIdx.x & 63;
    const int wid     = gtid >> 6;              // global wave id
    const int nwaves  = NB1 * 4;
    const int ngroups = (num_cand + CPW - 1) / CPW;
    const int rep     = wid & (NREP - 1);

    const float4 g = *reinterpret_cast<const float4*>(inj + lane * 4);
    float ng = g.x * g.x + g.y * g.y + g.z * g.z + g.w * g.w;
    #pragma unroll
    for (int off = 32; off > 0; off >>= 1) ng += __shfl_xor(ng, off);
    const float inj_n = fmaxf(sqrtf(ng), EPS_F);

    for (int grp = wid; grp < ngroups; grp += nwaves) {
        const int base   = grp * CPW;
        const int n_here = num_cand - base;   // >= 1

        const int r0 = cand[base];
        const int r1 = (n_here > 1) ? cand[base + 1] : r0;
        const int r2 = (n_here > 2) ? cand[base + 2] : r0;
        const int r3 = (n_here > 3) ? cand[base + 3] : r0;
        const float4 f0 = *reinterpret_cast<const float4*>(feats + (size_t)r0 * FEAT + lane * 4);
        const float4 f1 = *reinterpret_cast<const float4*>(feats + (size_t)r1 * FEAT + lane * 4);
        const float4 f2 = *reinterpret_cast<const float4*>(feats + (size_t)r2 * FEAT + lane * 4);
        const float4 f3 = *reinterpret_cast<const float4*>(feats + (size_t)r3 * FEAT + lane * 4);

        float dot0 = f0.x*g.x + f0.y*g.y + f0.z*g.z + f0.w*g.w;
        float nf0  = f0.x*f0.x + f0.y*f0.y + f0.z*f0.z + f0.w*f0.w;
        float dot1 = f1.x*g.x + f1.y*g.y + f1.z*g.z + f1.w*g.w;
        float nf1  = f1.x*f1.x + f1.y*f1.y + f1.z*f1.z + f1.w*f1.w;
        float dot2 = f2.x*g.x + f2.y*g.y + f2.z*g.z + f2.w*g.w;
        float nf2  = f2.x*f2.x + f2.y*f2.y + f2.z*f2.z + f2.w*f2.w;
        float dot3 = f3.x*g.x + f3.y*g.y + f3.z*g.z + f3.w*g.w;
        float nf3  = f3.x*f3.x + f3.y*f3.y + f3.z*f3.z + f3.w*f3.w;

        #pragma unroll
        for (int off = 32; off > 0; off >>= 1) {
            dot0 += __shfl_xor(dot0, off);  nf0 += __shfl_xor(nf0, off);
            dot1 += __shfl_xor(dot1, off);  nf1 += __shfl_xor(nf1, off);
            dot2 += __shfl_xor(dot2, off);  nf2 += __shfl_xor(nf2, off);
            dot3 += __shfl_xor(dot3, off);  nf3 += __shfl_xor(nf3, off);
        }

        if (lane == 0) {
            const float s0 = infl[base] - GAMMA_F * (dot0 / (fmaxf(sqrtf(nf0), EPS_F) * inj_n));
            if (n_here >= 4) {
                const float s1 = infl[base+1] - GAMMA_F * (dot1 / (fmaxf(sqrtf(nf1), EPS_F) * inj_n));
                const float s2 = infl[base+2] - GAMMA_F * (dot2 / (fmaxf(sqrtf(nf2), EPS_F) * inj_n));
                const float s3 = infl[base+3] - GAMMA_F * (dot3 / (fmaxf(sqrtf(nf3), EPS_F) * inj_n));
                *reinterpret_cast<float4*>(scores + base) = make_float4(s0, s1, s2, s3);
                atomicAdd(&ghist[(key_of(s0) >> KSHIFT) * NREP + rep], 1u);
                atomicAdd(&ghist[(key_of(s1) >> KSHIFT) * NREP + rep], 1u);
                atomicAdd(&ghist[(key_of(s2) >> KSHIFT) * NREP + rep], 1u);
                atomicAdd(&ghist[(key_of(s3) >> KSHIFT) * NREP + rep], 1u);
            } else {
                scores[base] = s0;
                atomicAdd(&ghist[(key_of(s0) >> KSHIFT) * NREP + rep], 1u);
                if (n_here > 1) {
                    const float s1 = infl[base+1] - GAMMA_F * (dot1 / (fmaxf(sqrtf(nf1), EPS_F) * inj_n));
                    scores[base+1] = s1;
                    atomicAdd(&ghist[(key_of(s1) >> KSHIFT) * NREP + rep], 1u);
                }
                if (n_here > 2) {
                    const float s2 = infl[base+2] - GAMMA_F * (dot2 / (fmaxf(sqrtf(nf2), EPS_F) * inj_n));
                    scores[base+2] = s2;
                    atomicAdd(&ghist[(key_of(s2) >> KSHIFT) * NREP + rep], 1u);
                }
            }
        }
    }
}

// ---------------------------------------------------------------------------
// Kernel 2: select. Each block redundantly computes threshold bucket B
// (suffix-scan of the replica-summed histogram, L2-hot), compacts its
// grid-stride slice's survivors into a PRIVATE 64-slot region (plain stores,
// no contended return-atomics). Last-finished block (ticket) prefix-sums the
// region counts, assembles survivors in LDS, bitonic-sorts 256 slots
// (value desc, index asc) and writes the top-64 node indices.
// ---------------------------------------------------------------------------
__global__ __launch_bounds__(256) void select_kernel(
    const float*    __restrict__ scores,
    const unsigned* __restrict__ ghist,     // [NBUCK][NREP]
    unsigned*       __restrict__ counts,    // [NB3]
    unsigned*       __restrict__ done,
    unsigned*       __restrict__ oflow,     // flag + spare (2 words)
    float*          __restrict__ ws_v,      // [NB3*BCAP]
    int*            __restrict__ ws_i,      // [NB3*BCAP]
    const int*      __restrict__ cand,
    float*          __restrict__ out,       // d_out[0..KSEL)
    int n)
{
    __shared__ unsigned csum[256];
    __shared__ unsigned sB, sCnt;
    __shared__ int      sLast;
    __shared__ unsigned soff[NB3 + 1];
    __shared__ float    sv[CAP];
    __shared__ int      si[CAP];

    const int t   = threadIdx.x;
    const int bid = blockIdx.x;

    // --- 1. threshold bucket B (redundant per block; ghist is L2-hot) ---
    {
        const int hi = NBUCK - 16 * t;     // chunk t = buckets [hi-16, hi)
        unsigned s = 0;
        for (int b = hi - 16; b < hi; ++b) {
            const uint4* r4 = reinterpret_cast<const uint4*>(&ghist[b * NREP]);
            #pragma unroll
            for (int q = 0; q < NREP / 4; ++q) {
                const uint4 a = r4[q];
                s += a.x + a.y + a.z + a.w;
            }
        }
        csum[t] = s;
    }
    __syncthreads();
    if (t == 0) {
        unsigned cum = 0;
        int tc = 0;
        for (; tc < 256; ++tc) {
            if (cum + csum[tc] >= KSEL) break;
            cum += csum[tc];
        }
        unsigned B = 0;
        if (tc < 256) {
            int b = NBUCK - 16 * tc - 1;
            for (int k = 0; k < 16; ++k, --b) {
                unsigned cb = 0;
                #pragma unroll
                for (int r = 0; r < NREP; ++r) cb += ghist[b * NREP + r];
                cum += cb;
                if (cum >= KSEL) { B = (unsigned)b; break; }
            }
        }
        sB = B;
        sCnt = 0;
    }
    __syncthreads();
    const unsigned B = sB;

    // --- 2. compact slice survivors into the block's private region ---
    const int n4 = n >> 2;
    const float4* s4 = reinterpret_cast<const float4*>(scores);
    for (int g = bid * 256 + t; g < n4; g += NB3 * 256) {
        const float4 v = s4[g];
        const float vv[4] = {v.x, v.y, v.z, v.w};
        #pragma unroll
        for (int j = 0; j < 4; ++j) {
            if ((key_of(vv[j]) >> KSHIFT) >= B) {
                const unsigned p = atomicAdd(&sCnt, 1u);   // LDS atomic
                if (p < BCAP) { ws_v[bid * BCAP + p] = vv[j]; ws_i[bid * BCAP + p] = g * 4 + j; }
            }
        }
    }
    if (bid == 0 && t < (n & 3)) {
        const float v = scores[n4 * 4 + t];
        if ((key_of(v) >> KSHIFT) >= B) {
            const unsigned p = atomicAdd(&sCnt, 1u);
            if (p < BCAP) { ws_v[p] = v; ws_i[p] = n4 * 4 + t; }
        }
    }
    __syncthreads();
    if (t == 0) {
        counts[bid] = min(sCnt, (unsigned)BCAP);
        if (sCnt > BCAP) atomicAdd(&oflow[0], 1u);   // never expected
    }

    // --- ticket: last-finished block assembles + sorts ---
    __threadfence();
    __syncthreads();
    if (t == 0) sLast = (atomicAdd(done, 1u) == (unsigned)(NB3 - 1));
    __syncthreads();
    if (!sLast) return;
    __threadfence();

    int m;
    if (oflow[0] == 0u) {
        // prefix offsets over the 64 region counts
        if (t == 0) {
            unsigned acc = 0;
            #pragma unroll
            for (int r = 0; r < NB3; ++r) { soff[r] = acc; acc += counts[r]; }
            soff[NB3] = acc;
        }
        __syncthreads();
        m = (int)soff[NB3];
        for (int idx = t; idx < NB3 * BCAP; idx += 256) {
            const int r = idx >> 6, j = idx & (BCAP - 1);
            if ((unsigned)j < counts[r]) {
                const unsigned dst = soff[r] + j;
                sv[dst] = ws_v[r * BCAP + j];
                si[dst] = ws_i[r * BCAP + j];
            }
        }
    } else {
        // Safety fallback: solo re-compact into LDS (never expected).
        if (t == 0) sCnt = 0;
        __syncthreads();
        for (int g = t; g < n; g += 256) {
            const float v = scores[g];
            if ((key_of(v) >> KSHIFT) >= B) {
                const unsigned p = atomicAdd(&sCnt, 1u);
                if (p < CAP) { sv[p] = v; si[p] = g; }
            }
        }
        __syncthreads();
        m = (int)min(sCnt, (unsigned)CAP);
    }
    __syncthreads();

    if (m <= 256) {
        // bitonic sort of 256 slots: value desc, index asc (lax.top_k order)
        if (t >= m) { sv[t] = -INFINITY; si[t] = INT_MAX; }
        __syncthreads();
        for (int k = 2; k <= 256; k <<= 1) {
            for (int j = k >> 1; j > 0; j >>= 1) {
                const int p = t ^ j;
                if (p > t) {
                    const float va = sv[t], vb = sv[p];
                    const int   ia = si[t], ib = si[p];
                    const bool asc = ((t & k) == 0);
                    const bool doSwap = asc ? comes_first(vb, ib, va, ia)
                                            : comes_first(va, ia, vb, ib);
                    if (doSwap) { sv[t] = vb; si[t] = ib; sv[p] = va; si[p] = ia; }
                }
                __syncthreads();
            }
        }
        if (t < KSEL) out[t] = (float)cand[si[t]];
        return;
    }

    // Fallback: serial argmax over m <= CAP survivors (never expected).
    __shared__ float wv[4];
    __shared__ int   wbi[4], wbs[4];
    for (int i = t + m; i < CAP; i += 256) { sv[i] = -INFINITY; si[i] = INT_MAX; }
    __syncthreads();
    for (int k = 0; k < KSEL; ++k) {
        float bv = -INFINITY; int bi = INT_MAX; int bs = 0;
        for (int i = t; i < CAP; i += 256) {
            if (comes_first(sv[i], si[i], bv, bi)) { bv = sv[i]; bi = si[i]; bs = i; }
        }
        #pragma unroll
        for (int off = 32; off > 0; off >>= 1) {
            const float ov = __shfl_xor(bv, off);
            const int   oi = __shfl_xor(bi, off);
            const int   os = __shfl_xor(bs, off);
            if (comes_first(ov, oi, bv, bi)) { bv = ov; bi = oi; bs = os; }
        }
        const int w = t >> 6;
        if ((t & 63) == 0) { wv[w] = bv; wbi[w] = bi; wbs[w] = bs; }
        __syncthreads();
        if (t == 0) {
            float fv = wv[0]; int fi = wbi[0]; int fs = wbs[0];
            #pragma unroll
            for (int j = 1; j < 4; ++j)
                if (comes_first(wv[j], wbi[j], fv, fi)) { fv = wv[j]; fi = wbi[j]; fs = wbs[j]; }
            out[k] = (float)cand[fi];
            sv[fs] = -INFINITY;
            si[fs] = INT_MAX;
        }
        __syncthreads();
    }
}

extern "C" void kernel_launch(void* const* d_in, const int* in_sizes, int n_in,
                              void* d_out, int out_size, void* d_ws, size_t ws_size,
                              hipStream_t stream) {
    const float* infl  = (const float*)d_in[0];   // [num_cand]
    const float* feats = (const float*)d_in[1];   // [num_nodes, 256]
    const int*   cand  = (const int*)d_in[2];     // [num_cand]
    const float* inj   = (const float*)d_in[3];   // [256]

    const int num_cand = in_sizes[0];

    float* out    = (float*)d_out;          // [0..64): indices-as-f32
    float* scores = (float*)d_out + KSEL;   // [64..64+num_cand): edge scores

    unsigned* ws_ghist  = (unsigned*)d_ws;               // NBUCK*NREP
    unsigned* ws_counts = ws_ghist + NBUCK * NREP;       // NB3
    unsigned* ws_done   = ws_counts + NB3;               // 1
    unsigned* ws_oflow  = ws_done + 1;                   // 2
    float*    ws_v      = (float*)(ws_oflow + 2);        // NB3*BCAP
    int*      ws_i      = (int*)(ws_v + NB3 * BCAP);     // NB3*BCAP

    // 0. Zero replicated histogram + counters (~256 KB, ~0.1 us fill).
    hipMemsetAsync(ws_ghist, 0, (NBUCK * NREP + NB3 + 3) * sizeof(unsigned), stream);

    // 1. Fused edge scores + replicated histogram (persistent grid).
    edge_score_kernel<<<NB1, 256, 0, stream>>>(
        infl, feats, cand, inj, scores, ws_ghist, num_cand);

    // 2. Threshold + contention-free compact + final top-64.
    select_kernel<<<NB3, 256, 0, stream>>>(
        scores, ws_ghist, ws_counts, ws_done, ws_oflow, ws_v, ws_i, cand, out, num_cand);
}

// Round 8
// 50.898 us; speedup vs baseline: 1.4535x; 1.4535x over previous
//
#include <hip/hip_runtime.h>
#include <hip/hip_bf16.h>
#include <float.h>
#include <limits.h>

#define FEAT       256
#define GAMMA_F    0.1f
#define EPS_F      1e-8f
#define KSEL       64        // BUDGET
#define NBUCK      16384     // influence histogram buckets (64 KB LDS)
#define KSHIFT     18        // key >> KSHIFT -> bucket
#define NB1        2048      // persistent score blocks (8192 waves = 100% occ)
#define CPW        4         // candidates per wave
#define CAP        2048      // survivor capacity (expected ~160 used)
#define TMARGIN    0.21f     // > 2*GAMMA + eps: |score - infl| <= 0.1

// Monotonic float -> uint transform (ascending order preserved).
__device__ __forceinline__ unsigned key_of(float v) {
    unsigned u = __float_as_uint(v);
    return u ^ ((u >> 31) ? 0xFFFFFFFFu : 0x80000000u);
}

__device__ __forceinline__ bool comes_first(float va, int ia, float vb, int ib) {
    return (va > vb) || (va == vb && ia < ib);
}

// ---------------------------------------------------------------------------
// Kernel 0: ONE block. LDS histogram of influence_scores (200 KB read),
// suffix-scan for the bucket B holding the 64th-largest influence, then
// T_filter = lowest_float(B) - 0.21. Bound: top-64 edge-score candidates all
// have infl >= S64-0.1 >= T64-0.2 >= bucket_lo(B)-0.2 > T_filter, ties incl.
// Also zeroes the survivor counter (kernel-boundary ordering -> K1 sees 0).
// No global histogram, no memset node, no contended atomics.
// ---------------------------------------------------------------------------
__global__ __launch_bounds__(256) void infl_thresh_kernel(
    const float* __restrict__ infl,
    float*       __restrict__ meta,    // [0] = T_filter
    unsigned*    __restrict__ gcnt,    // zeroed here for K1
    int n)
{
    __shared__ unsigned h[NBUCK];      // 64 KB
    __shared__ unsigned csum[256];
    const int t = threadIdx.x;

    for (int i = t; i < NBUCK; i += 256) h[i] = 0;
    __syncthreads();

    const int n4 = n >> 2;
    const float4* f4 = reinterpret_cast<const float4*>(infl);
    for (int g = t; g < n4; g += 256) {
        const float4 v = f4[g];
        atomicAdd(&h[key_of(v.x) >> KSHIFT], 1u);
        atomicAdd(&h[key_of(v.y) >> KSHIFT], 1u);
        atomicAdd(&h[key_of(v.z) >> KSHIFT], 1u);
        atomicAdd(&h[key_of(v.w) >> KSHIFT], 1u);
    }
    if (t < (n & 3)) atomicAdd(&h[key_of(infl[n4 * 4 + t]) >> KSHIFT], 1u);
    __syncthreads();

    // suffix-scan: chunk t = buckets [NBUCK-64(t+1), NBUCK-64t)
    {
        const int hi = NBUCK - 64 * t;
        unsigned s = 0;
        for (int b = hi - 64; b < hi; ++b) s += h[b];
        csum[t] = s;
    }
    __syncthreads();

    if (t == 0) {
        unsigned cum = 0;
        int tc = 0;
        for (; tc < 256; ++tc) {
            if (cum + csum[tc] >= KSEL) break;
            cum += csum[tc];
        }
        unsigned B = 0;
        if (tc < 256) {
            int b = NBUCK - 64 * tc - 1;
            for (int k = 0; k < 64; ++k, --b) {
                cum += h[b];
                if (cum >= KSEL) { B = (unsigned)b; break; }
            }
        }
        // lowest float in bucket B (invert the monotonic key transform)
        const unsigned key_lo = B << KSHIFT;
        const unsigned u = (key_lo & 0x80000000u) ? (key_lo ^ 0x80000000u) : ~key_lo;
        meta[0] = __uint_as_float(u) - TMARGIN;
        gcnt[0] = 0u;
    }
}

// ---------------------------------------------------------------------------
// Kernel 1: edge scores (round-6 proven structure). Persistent grid, CPW=4
// independent 1 KB row-gathers in flight per wave, ||inj|| hoisted, float4
// score stores. NEW: lane 0 appends candidates with infl >= T_filter to the
// survivor list (~160 total atomics across the whole grid -- genuinely
// uncontended, unlike R3/R7's 50000).
// ---------------------------------------------------------------------------
__global__ __launch_bounds__(256) void edge_score_kernel(
    const float* __restrict__ infl,
    const float* __restrict__ feats,
    const int*   __restrict__ cand,
    const float* __restrict__ inj,
    const float* __restrict__ meta,     // [0] = T_filter
    unsigned*    __restrict__ gcnt,
    float*       __restrict__ ws_v,     // [CAP]
    int*         __restrict__ ws_i,     // [CAP]
    float*       __restrict__ scores,   // d_out + KSEL
    int num_cand)
{
    const int gtid    = blockIdx.x * blockDim.x + threadIdx.x;
    const int lane    = threadIdx.x & 63;
    const int wid     = gtid >> 6;
    const int nwaves  = NB1 * 4;
    const int ngroups = (num_cand + CPW - 1) / CPW;
    const float T     = meta[0];

    const float4 g = *reinterpret_cast<const float4*>(inj + lane * 4);
    float ng = g.x * g.x + g.y * g.y + g.z * g.z + g.w * g.w;
    #pragma unroll
    for (int off = 32; off > 0; off >>= 1) ng += __shfl_xor(ng, off);
    const float inj_n = fmaxf(sqrtf(ng), EPS_F);

    for (int grp = wid; grp < ngroups; grp += nwaves) {
        const int base   = grp * CPW;
        const int n_here = num_cand - base;   // >= 1

        const int r0 = cand[base];
        const int r1 = (n_here > 1) ? cand[base + 1] : r0;
        const int r2 = (n_here > 2) ? cand[base + 2] : r0;
        const int r3 = (n_here > 3) ? cand[base + 3] : r0;
        const float4 f0 = *reinterpret_cast<const float4*>(feats + (size_t)r0 * FEAT + lane * 4);
        const float4 f1 = *reinterpret_cast<const float4*>(feats + (size_t)r1 * FEAT + lane * 4);
        const float4 f2 = *reinterpret_cast<const float4*>(feats + (size_t)r2 * FEAT + lane * 4);
        const float4 f3 = *reinterpret_cast<const float4*>(feats + (size_t)r3 * FEAT + lane * 4);

        float dot0 = f0.x*g.x + f0.y*g.y + f0.z*g.z + f0.w*g.w;
        float nf0  = f0.x*f0.x + f0.y*f0.y + f0.z*f0.z + f0.w*f0.w;
        float dot1 = f1.x*g.x + f1.y*g.y + f1.z*g.z + f1.w*g.w;
        float nf1  = f1.x*f1.x + f1.y*f1.y + f1.z*f1.z + f1.w*f1.w;
        float dot2 = f2.x*g.x + f2.y*g.y + f2.z*g.z + f2.w*g.w;
        float nf2  = f2.x*f2.x + f2.y*f2.y + f2.z*f2.z + f2.w*f2.w;
        float dot3 = f3.x*g.x + f3.y*g.y + f3.z*g.z + f3.w*g.w;
        float nf3  = f3.x*f3.x + f3.y*f3.y + f3.z*f3.z + f3.w*f3.w;

        #pragma unroll
        for (int off = 32; off > 0; off >>= 1) {
            dot0 += __shfl_xor(dot0, off);  nf0 += __shfl_xor(nf0, off);
            dot1 += __shfl_xor(dot1, off);  nf1 += __shfl_xor(nf1, off);
            dot2 += __shfl_xor(dot2, off);  nf2 += __shfl_xor(nf2, off);
            dot3 += __shfl_xor(dot3, off);  nf3 += __shfl_xor(nf3, off);
        }

        if (lane == 0) {
            const float i0 = infl[base];
            const float s0 = i0 - GAMMA_F * (dot0 / (fmaxf(sqrtf(nf0), EPS_F) * inj_n));
            if (n_here >= 4) {
                const float i1 = infl[base+1], i2 = infl[base+2], i3 = infl[base+3];
                const float s1 = i1 - GAMMA_F * (dot1 / (fmaxf(sqrtf(nf1), EPS_F) * inj_n));
                const float s2 = i2 - GAMMA_F * (dot2 / (fmaxf(sqrtf(nf2), EPS_F) * inj_n));
                const float s3 = i3 - GAMMA_F * (dot3 / (fmaxf(sqrtf(nf3), EPS_F) * inj_n));
                *reinterpret_cast<float4*>(scores + base) = make_float4(s0, s1, s2, s3);
                if (i0 >= T) { const unsigned p = atomicAdd(gcnt, 1u); if (p < CAP) { ws_v[p] = s0; ws_i[p] = base;     } }
                if (i1 >= T) { const unsigned p = atomicAdd(gcnt, 1u); if (p < CAP) { ws_v[p] = s1; ws_i[p] = base + 1; } }
                if (i2 >= T) { const unsigned p = atomicAdd(gcnt, 1u); if (p < CAP) { ws_v[p] = s2; ws_i[p] = base + 2; } }
                if (i3 >= T) { const unsigned p = atomicAdd(gcnt, 1u); if (p < CAP) { ws_v[p] = s3; ws_i[p] = base + 3; } }
            } else {
                scores[base] = s0;
                if (i0 >= T) { const unsigned p = atomicAdd(gcnt, 1u); if (p < CAP) { ws_v[p] = s0; ws_i[p] = base; } }
                if (n_here > 1) {
                    const float i1 = infl[base+1];
                    const float s1 = i1 - GAMMA_F * (dot1 / (fmaxf(sqrtf(nf1), EPS_F) * inj_n));
                    scores[base+1] = s1;
                    if (i1 >= T) { const unsigned p = atomicAdd(gcnt, 1u); if (p < CAP) { ws_v[p] = s1; ws_i[p] = base + 1; } }
                }
                if (n_here > 2) {
                    const float i2 = infl[base+2];
                    const float s2 = i2 - GAMMA_F * (dot2 / (fmaxf(sqrtf(nf2), EPS_F) * inj_n));
                    scores[base+2] = s2;
                    if (i2 >= T) { const unsigned p = atomicAdd(gcnt, 1u); if (p < CAP) { ws_v[p] = s2; ws_i[p] = base + 2; } }
                }
            }
        }
    }
}

// ---------------------------------------------------------------------------
// Kernel 2: ONE block. Exact top-64 over the ~160 survivors: 256-slot bitonic
// sort (value desc, index asc = lax.top_k order); serial-argmax fallback for
// 256 < m <= CAP (never expected). Writes node indices as f32.
// ---------------------------------------------------------------------------
__global__ __launch_bounds__(256) void final_kernel(
    const unsigned* __restrict__ gcnt,
    const float*    __restrict__ ws_v,
    const int*      __restrict__ ws_i,
    const int*      __restrict__ cand,
    float*          __restrict__ out)   // d_out[0..KSEL)
{
    __shared__ float sv[CAP];
    __shared__ int   si[CAP];
    const int t = threadIdx.x;
    const int m = (int)min(*gcnt, (unsigned)CAP);

    if (m <= 256) {
        sv[t] = (t < m) ? ws_v[t] : -INFINITY;
        si[t] = (t < m) ? ws_i[t] : INT_MAX;
        __syncthreads();
        for (int k = 2; k <= 256; k <<= 1) {
            for (int j = k >> 1; j > 0; j >>= 1) {
                const int p = t ^ j;
                if (p > t) {
                    const float va = sv[t], vb = sv[p];
                    const int   ia = si[t], ib = si[p];
                    const bool asc = ((t & k) == 0);
                    const bool doSwap = asc ? comes_first(vb, ib, va, ia)
                                            : comes_first(va, ia, vb, ib);
                    if (doSwap) { sv[t] = vb; si[t] = ib; sv[p] = va; si[p] = ia; }
                }
                __syncthreads();
            }
        }
        if (t < KSEL) out[t] = (float)cand[si[t]];
        return;
    }

    // Fallback: serial argmax over m <= CAP survivors (never expected).
    __shared__ float wv[4];
    __shared__ int   wbi[4], wbs[4];
    for (int i = t; i < CAP; i += 256) {
        sv[i] = (i < m) ? ws_v[i] : -INFINITY;
        si[i] = (i < m) ? ws_i[i] : INT_MAX;
    }
    __syncthreads();
    for (int k = 0; k < KSEL; ++k) {
        float bv = -INFINITY; int bi = INT_MAX; int bs = 0;
        for (int i = t; i < CAP; i += 256) {
            if (comes_first(sv[i], si[i], bv, bi)) { bv = sv[i]; bi = si[i]; bs = i; }
        }
        #pragma unroll
        for (int off = 32; off > 0; off >>= 1) {
            const float ov = __shfl_xor(bv, off);
            const int   oi = __shfl_xor(bi, off);
            const int   os = __shfl_xor(bs, off);
            if (comes_first(ov, oi, bv, bi)) { bv = ov; bi = oi; bs = os; }
        }
        const int w = t >> 6;
        if ((t & 63) == 0) { wv[w] = bv; wbi[w] = bi; wbs[w] = bs; }
        __syncthreads();
        if (t == 0) {
            float fv = wv[0]; int fi = wbi[0]; int fs = wbs[0];
            #pragma unroll
            for (int j = 1; j < 4; ++j)
                if (comes_first(wv[j], wbi[j], fv, fi)) { fv = wv[j]; fi = wbi[j]; fs = wbs[j]; }
            out[k] = (float)cand[fi];
            sv[fs] = -INFINITY;
            si[fs] = INT_MAX;
        }
        __syncthreads();
    }
}

extern "C" void kernel_launch(void* const* d_in, const int* in_sizes, int n_in,
                              void* d_out, int out_size, void* d_ws, size_t ws_size,
                              hipStream_t stream) {
    const float* infl  = (const float*)d_in[0];   // [num_cand]
    const float* feats = (const float*)d_in[1];   // [num_nodes, 256]
    const int*   cand  = (const int*)d_in[2];     // [num_cand]
    const float* inj   = (const float*)d_in[3];   // [256]

    const int num_cand = in_sizes[0];

    float* out    = (float*)d_out;          // [0..64): indices-as-f32
    float* scores = (float*)d_out + KSEL;   // [64..64+num_cand): edge scores

    float*    ws_meta = (float*)d_ws;                 // 1 (T_filter)
    unsigned* ws_cnt  = (unsigned*)(ws_meta + 1);     // 1
    float*    ws_v    = (float*)(ws_cnt + 1);         // CAP
    int*      ws_i    = (int*)(ws_v + CAP);           // CAP

    // 0. Influence threshold (1 block, LDS-only hist) + zero survivor count.
    infl_thresh_kernel<<<1, 256, 0, stream>>>(infl, ws_meta, ws_cnt, num_cand);

    // 1. Edge scores (persistent grid) + filtered survivor append.
    edge_score_kernel<<<NB1, 256, 0, stream>>>(
        infl, feats, cand, inj, ws_meta, ws_cnt, ws_v, ws_i, scores, num_cand);

    // 2. Exact top-64 over survivors (1 block).
    final_kernel<<<1, 256, 0, stream>>>(ws_cnt, ws_v, ws_i, cand, out);
}